// Round 21
// baseline (110.808 us; speedup 1.0000x reference)
//
#include <hip/hip_runtime.h>
#include <math.h>

typedef float f32x4 __attribute__((ext_vector_type(4)));
typedef __attribute__((address_space(3))) unsigned int lds_u32;
typedef __attribute__((address_space(1))) const unsigned int glb_u32;

// ---------------------------------------------------------------------------
// Kernel 1: row normalization (8 rows per block, 32 lanes per row) + zero
// unsim/psum/accum. Output: fp8 e4m3 rows PRE-SWIZZLED: 16B chunk c of row r
// stored at chunk (c ^ (r&7)); pass1 stages rows verbatim with async
// global_load_lds and reads with the same swizzle.
__global__ __launch_bounds__(256) void norm_kernel(
    const float* __restrict__ X, unsigned char* __restrict__ Y8,
    float* __restrict__ unsim, float* __restrict__ psum,
    float* __restrict__ accum, float inv_sqrtT) {
  int t = threadIdx.x;
  int row = blockIdx.x * 8 + (t >> 5);
  int l32 = t & 31;
  float4 v = ((const float4*)(X + (size_t)row * 128))[l32];
  float s = v.x * v.x + v.y * v.y + v.z * v.z + v.w * v.w;
  s += __shfl_xor(s, 1);
  s += __shfl_xor(s, 2);
  s += __shfl_xor(s, 4);
  s += __shfl_xor(s, 8);
  s += __shfl_xor(s, 16);
  float inv = inv_sqrtT * rsqrtf(fmaxf(s, 1e-24f));
  int pk = __builtin_amdgcn_cvt_pk_fp8_f32(v.x * inv, v.y * inv, 0, false);
  pk = __builtin_amdgcn_cvt_pk_fp8_f32(v.z * inv, v.w * inv, pk, true);
  int chunk = l32 >> 2;
  int off = ((chunk ^ (row & 7)) << 4) + ((l32 & 3) << 2);
  *(unsigned int*)(Y8 + (size_t)row * 128 + off) = (unsigned)pk;
  if (t < 8) unsim[blockIdx.x * 8 + t] = 0.f;
  else if (t < 16) psum[blockIdx.x * 8 + (t - 8)] = 0.f;
  if (blockIdx.x == 0 && t >= 224 && t < 232) accum[t - 224] = 0.f;
}

// ---------------------------------------------------------------------------
// Kernel 2: fp8 MFMA similarity pass over upper-triangular 128x128 tile
// pairs. 1024-thread blocks, 16 waves, each a 16x64 quadrant (acc[1][4]):
// same tile / staging bytes / block count as R19-R20, half the per-wave
// work — 2 blocks/CU x 16 waves = 32 waves/CU (hardware max). Algebra:
//   unsim_i = sum_{j!=i} exp(s_ij)  (= u + p), psum_i = sum_pos exp(s_ij),
//   accum[4] += sum_pos s. Branch-free totals; rare (1/128) LDS-atomic path.
// NO __threadfence (measured +33 us over 2080 blocks, R17/R18 vs R19).
__global__ __launch_bounds__(1024, 8) void pass1_kernel(
    const unsigned char* __restrict__ Y8, const int* __restrict__ lab,
    float* __restrict__ unsim, float* __restrict__ psumG,
    float* __restrict__ accum, int nt) {
  __shared__ unsigned char As[128][128];  // chunk c at (c ^ (row&7)) * 16
  __shared__ unsigned char Bs[128][128];
  __shared__ int labR[128], labC[128];
  __shared__ float tsumS[128], tcolS[128];
  __shared__ float psumS[256];  // [0:128) rows, [128:256) cols
  __shared__ float diagS[128];
  __shared__ float sS[16];

  // decode linear block id -> (bi, bj), bi <= bj (triangular)
  int b = blockIdx.x;
  float ntf = (float)nt;
  int bi = (int)((2.f * ntf + 1.f -
                  sqrtf((2.f * ntf + 1.f) * (2.f * ntf + 1.f) - 8.f * (float)b)) *
                 0.5f);
  if (bi < 0) bi = 0;
  while ((bi + 1) * nt - ((bi + 1) * bi) / 2 <= b) ++bi;
  while (bi * nt - (bi * (bi - 1)) / 2 > b) --bi;
  int bj = bi + (b - (bi * nt - (bi * (bi - 1)) / 2));
  const int i0 = bi * 128, j0 = bj * 128;
  const bool offdiag = (bi != bj);

  const int t = threadIdx.x;
  const int w = t >> 6, lane = t & 63;

  // ---- async staging: exactly one A + one B 1KB segment per wave ----
  {
    const int c0 = w * 64;  // wave-uniform 16B-chunk index
    const int c = c0 + lane;
    __builtin_amdgcn_global_load_lds(
        (glb_u32*)(Y8 + (size_t)i0 * 128 + (size_t)c * 16),
        (lds_u32*)((unsigned char*)&As[0][0] + c0 * 16), 16, 0, 0);
    __builtin_amdgcn_global_load_lds(
        (glb_u32*)(Y8 + (size_t)j0 * 128 + (size_t)c * 16),
        (lds_u32*)((unsigned char*)&Bs[0][0] + c0 * 16), 16, 0, 0);
  }
  if (t < 128) {
    labR[t] = lab[i0 + t];
    tsumS[t] = 0.f;
    psumS[t] = 0.f;
    diagS[t] = 0.f;
  } else if (t < 256) {
    labC[t - 128] = lab[j0 + t - 128];
    tcolS[t - 128] = 0.f;
    psumS[t] = 0.f;
  }
  __syncthreads();  // drains vmcnt (global_load_lds) + lgkmcnt

  const int quad = lane >> 4, l16 = lane & 15;
  const int rbase = (w >> 1) * 16, cbase = (w & 1) * 64;  // 16x64 quadrant
  const int sw = l16 & 7;

  f32x4 acc[4] = {};
#pragma unroll
  for (int ks = 0; ks < 4; ++ks) {
    const int ch = ks * 2 + (quad >> 1);
    const int off = ((ch ^ sw) << 4) + ((quad & 1) << 3);
    long af = *(const long*)&As[rbase + l16][off];
    long bf[4];
#pragma unroll
    for (int p = 0; p < 4; ++p)
      bf[p] = *(const long*)&Bs[cbase + p * 16 + l16][off];
#pragma unroll
    for (int pj = 0; pj < 4; ++pj)
      acc[pj] = __builtin_amdgcn_mfma_f32_16x16x32_fp8_fp8(af, bf[pj],
                                                           acc[pj], 0, 0, 0);
  }

  // ---- epilogue: branch-free totals + rare positive/diag path ----
  int lr[4], lc[4];
#pragma unroll
  for (int r = 0; r < 4; ++r) lr[r] = labR[rbase + quad * 4 + r];
#pragma unroll
  for (int pj = 0; pj < 4; ++pj) lc[pj] = labC[cbase + pj * 16 + l16];

  float trow[4] = {0.f, 0.f, 0.f, 0.f};
  float tcol[4] = {0.f, 0.f, 0.f, 0.f};
  float sacc = 0.f;
#pragma unroll
  for (int pj = 0; pj < 4; ++pj)
#pragma unroll
    for (int r = 0; r < 4; ++r) {
      const float s = acc[pj][r];
      const float e = __expf(s);
      trow[r] += e;
      tcol[pj] += e;
      if (lr[r] == lc[pj]) {  // rare: 1/128
        const int row = rbase + quad * 4 + r;
        const int col = cbase + pj * 16 + l16;
        if (offdiag) {
          atomicAdd(&psumS[row], e);
          atomicAdd(&psumS[128 + col], e);
          sacc += 2.f * s;
        } else if (row != col) {
          atomicAdd(&psumS[row], e);
          sacc += s;
        } else {
          diagS[row] = e;  // unique writer
        }
      }
    }

  // row sums: 4-shfl reduce over the 16 cols, stage in LDS
#pragma unroll
  for (int r = 0; r < 4; ++r) {
    float v = trow[r];
    v += __shfl_xor(v, 1);
    v += __shfl_xor(v, 2);
    v += __shfl_xor(v, 4);
    v += __shfl_xor(v, 8);
    if (l16 == 0) atomicAdd(&tsumS[rbase + quad * 4 + r], v);
  }
  // col sums (mirror band): reduce across quads, stage in LDS
#pragma unroll
  for (int pj = 0; pj < 4; ++pj) {
    float v = tcol[pj];
    v += __shfl_xor(v, 16);
    v += __shfl_xor(v, 32);
    if (quad == 0) atomicAdd(&tcolS[cbase + pj * 16 + l16], v);
  }
  // block scalar: sum_pos s
#pragma unroll
  for (int m = 1; m < 64; m <<= 1) sacc += __shfl_xor(sacc, m);
  if (lane == 0) sS[w] = sacc;
  __syncthreads();

  // flush: unsim += t - diag (so unsim = u + p), psum += p; one scalar atomic
  if (t < 128) {
    atomicAdd(&unsim[i0 + t], tsumS[t] - diagS[t]);
    atomicAdd(&psumG[i0 + t], psumS[t]);
  } else if (t < 256 && offdiag) {
    atomicAdd(&unsim[j0 + (t - 128)], tcolS[t - 128]);
    atomicAdd(&psumG[j0 + (t - 128)], psumS[t]);
  }
  if (t == 0) {
    float st = 0.f;
#pragma unroll
    for (int i = 0; i < 16; ++i) st += sS[i];
    atomicAdd(&accum[4], st);
  }
}

// ---------------------------------------------------------------------------
// Kernel 3: finalize (one 1024-thread block):
//   loss_sum = sum_i [cnt_i*log(u_i) + p_i/u_i] - ssum,  u = unsim - p
//   n_pos    = sum_c m_c^2 - N;   out = loss_sum / n_pos
__global__ __launch_bounds__(1024) void finalize_kernel(
    const int* __restrict__ lab, const float* __restrict__ unsim,
    const float* __restrict__ psum, const float* __restrict__ accum,
    float* __restrict__ out, int N) {
  __shared__ int hist[256];
  __shared__ float redL[16], redN[16];
  int t = threadIdx.x;
  int lane = t & 63, w = t >> 6;
  if (t < 256) hist[t] = 0;
  __syncthreads();
  for (int i = t; i < N; i += 1024) atomicAdd(&hist[lab[i] & 255], 1);
  __syncthreads();
  float local = 0.f;
  for (int i = t; i < N; i += 1024) {
    float tot = unsim[i];
    float p = psum[i];
    float u = tot - p;
    float c = (float)(hist[lab[i] & 255] - 1);
    local += c * __logf(u) + p / u;
  }
  float nposl = 0.f;
  if (t < 256) {
    float m = (float)hist[t];
    nposl = m * m;
  }
#pragma unroll
  for (int msk = 1; msk < 64; msk <<= 1) {
    local += __shfl_xor(local, msk);
    nposl += __shfl_xor(nposl, msk);
  }
  if (lane == 0) {
    redL[w] = local;
    redN[w] = nposl;
  }
  __syncthreads();
  if (t == 0) {
    float ls = 0.f, np = 0.f;
#pragma unroll
    for (int i = 0; i < 16; ++i) {
      ls += redL[i];
      np += redN[i];
    }
    out[0] = (ls - accum[4]) / (np - (float)N);
  }
}

// ---------------------------------------------------------------------------
extern "C" void kernel_launch(void* const* d_in, const int* in_sizes, int n_in,
                              void* d_out, int out_size, void* d_ws,
                              size_t ws_size, hipStream_t stream) {
  const float* X = (const float*)d_in[0];
  const int* lab = (const int*)d_in[1];
  float* out = (float*)d_out;

  const int N = in_sizes[1];  // 8192; D fixed at 128

  // workspace layout
  unsigned char* Y8 = (unsigned char*)d_ws;       // N*128 fp8 (1 MB)
  float* unsim = (float*)(Y8 + (size_t)N * 128);  // N f32 (= u + p)
  float* psum = unsim + N;                        // N f32
  float* accum = psum + N;                        // [4] ssum

  const float inv_sqrtT = 2.2360679775f;  // 1/sqrt(0.2)
  norm_kernel<<<N / 8, 256, 0, stream>>>(X, Y8, unsim, psum, accum,
                                         inv_sqrtT);

  const int nt = N / 128;              // 64 tiles per dim
  const int nblk = nt * (nt + 1) / 2;  // 2080 upper-tri tile pairs
  pass1_kernel<<<nblk, 1024, 0, stream>>>(Y8, lab, unsim, psum, accum, nt);
  finalize_kernel<<<1, 1024, 0, stream>>>(lab, unsim, psum, accum, out, N);
}

// Round 22
// 105.397 us; speedup vs baseline: 1.0513x; 1.0513x over previous
//
#include <hip/hip_runtime.h>
#include <math.h>

typedef float f32x4 __attribute__((ext_vector_type(4)));
typedef __attribute__((address_space(3))) unsigned int lds_u32;
typedef __attribute__((address_space(1))) const unsigned int glb_u32;

// ---------------------------------------------------------------------------
// Kernel 1: row normalization (8 rows per block, 32 lanes per row) + zero
// unsim/psum/accum. Output: fp8 e4m3 rows PRE-SWIZZLED: 16B chunk c of row r
// stored at chunk (c ^ (r&7)); pass1 stages rows verbatim with async
// global_load_lds and reads with the same swizzle.
__global__ __launch_bounds__(256) void norm_kernel(
    const float* __restrict__ X, unsigned char* __restrict__ Y8,
    float* __restrict__ unsim, float* __restrict__ psum,
    float* __restrict__ accum, float inv_sqrtT) {
  int t = threadIdx.x;
  int row = blockIdx.x * 8 + (t >> 5);
  int l32 = t & 31;
  float4 v = ((const float4*)(X + (size_t)row * 128))[l32];
  float s = v.x * v.x + v.y * v.y + v.z * v.z + v.w * v.w;
  s += __shfl_xor(s, 1);
  s += __shfl_xor(s, 2);
  s += __shfl_xor(s, 4);
  s += __shfl_xor(s, 8);
  s += __shfl_xor(s, 16);
  float inv = inv_sqrtT * rsqrtf(fmaxf(s, 1e-24f));
  int pk = __builtin_amdgcn_cvt_pk_fp8_f32(v.x * inv, v.y * inv, 0, false);
  pk = __builtin_amdgcn_cvt_pk_fp8_f32(v.z * inv, v.w * inv, pk, true);
  int chunk = l32 >> 2;
  int off = ((chunk ^ (row & 7)) << 4) + ((l32 & 3) << 2);
  *(unsigned int*)(Y8 + (size_t)row * 128 + off) = (unsigned)pk;
  if (t < 8) unsim[blockIdx.x * 8 + t] = 0.f;
  else if (t < 16) psum[blockIdx.x * 8 + (t - 8)] = 0.f;
  if (blockIdx.x == 0 && t >= 224 && t < 232) accum[t - 224] = 0.f;
}

// ---------------------------------------------------------------------------
// Kernel 2 (FROZEN at R19/R20 — the measured optimum across 11 structural
// variants): fp8 MFMA similarity pass over upper-triangular 128x128 tile
// pairs. 512 thr, 8 waves x 32x64 quadrants, async global_load_lds staging
// of pre-swizzled Y8. Algebra:
//   unsim_i = sum_{j!=i} exp(s_ij)  (total minus diagonal; = u + p)
//   psum_i  = sum_{j pos} exp(s_ij),  accum[4] += sum_pos s
// Branch-free totals in the hot loop; rare (1/128) paths use LDS atomics.
// NO __threadfence here — measured +33 us over 2080 blocks (R17/R18 vs R19).
// Occupancy is anti-correlated with speed here (R5/R15/R21): per-block and
// per-wave fixed costs dominate, so 8x32x64 at 3 blocks/CU is the optimum.
__global__ __launch_bounds__(512, 6) void pass1_kernel(
    const unsigned char* __restrict__ Y8, const int* __restrict__ lab,
    float* __restrict__ unsim, float* __restrict__ psumG,
    float* __restrict__ accum, int nt) {
  __shared__ unsigned char As[128][128];  // chunk c at (c ^ (row&7)) * 16
  __shared__ unsigned char Bs[128][128];
  __shared__ int labR[128], labC[128];
  __shared__ float tsumS[128], tcolS[128];
  __shared__ float psumS[256];  // [0:128) rows, [128:256) cols
  __shared__ float diagS[128];
  __shared__ float sS[8];

  // decode linear block id -> (bi, bj), bi <= bj (triangular)
  int b = blockIdx.x;
  float ntf = (float)nt;
  int bi = (int)((2.f * ntf + 1.f -
                  sqrtf((2.f * ntf + 1.f) * (2.f * ntf + 1.f) - 8.f * (float)b)) *
                 0.5f);
  if (bi < 0) bi = 0;
  while ((bi + 1) * nt - ((bi + 1) * bi) / 2 <= b) ++bi;
  while (bi * nt - (bi * (bi - 1)) / 2 > b) --bi;
  int bj = bi + (b - (bi * nt - (bi * (bi - 1)) / 2));
  const int i0 = bi * 128, j0 = bj * 128;
  const bool offdiag = (bi != bj);

  const int t = threadIdx.x;
  const int w = t >> 6, lane = t & 63;

  // ---- async staging: 2 x (A,B) 1KB segments per wave (8 waves) ----
#pragma unroll
  for (int k = 0; k < 2; ++k) {
    const int c0 = w * 64 + k * 512;  // wave-uniform 16B-chunk index
    const int c = c0 + lane;
    __builtin_amdgcn_global_load_lds(
        (glb_u32*)(Y8 + (size_t)i0 * 128 + (size_t)c * 16),
        (lds_u32*)((unsigned char*)&As[0][0] + c0 * 16), 16, 0, 0);
    __builtin_amdgcn_global_load_lds(
        (glb_u32*)(Y8 + (size_t)j0 * 128 + (size_t)c * 16),
        (lds_u32*)((unsigned char*)&Bs[0][0] + c0 * 16), 16, 0, 0);
  }
  if (t < 128) {
    labR[t] = lab[i0 + t];
    tsumS[t] = 0.f;
    psumS[t] = 0.f;
    diagS[t] = 0.f;
  } else if (t < 256) {
    labC[t - 128] = lab[j0 + t - 128];
    tcolS[t - 128] = 0.f;
    psumS[t] = 0.f;
  }
  __syncthreads();  // drains vmcnt (global_load_lds) + lgkmcnt

  const int quad = lane >> 4, l16 = lane & 15;
  const int rbase = (w >> 1) * 32, cbase = (w & 1) * 64;  // 32x64 quadrant
  const int sw = l16 & 7;

  f32x4 acc[2][4] = {};
#pragma unroll
  for (int ks = 0; ks < 4; ++ks) {
    const int ch = ks * 2 + (quad >> 1);
    const int off = ((ch ^ sw) << 4) + ((quad & 1) << 3);
    long af[2], bf[4];
#pragma unroll
    for (int p = 0; p < 2; ++p)
      af[p] = *(const long*)&As[rbase + p * 16 + l16][off];
#pragma unroll
    for (int p = 0; p < 4; ++p)
      bf[p] = *(const long*)&Bs[cbase + p * 16 + l16][off];
#pragma unroll
    for (int pi = 0; pi < 2; ++pi)
#pragma unroll
      for (int pj = 0; pj < 4; ++pj)
        acc[pi][pj] = __builtin_amdgcn_mfma_f32_16x16x32_fp8_fp8(
            af[pi], bf[pj], acc[pi][pj], 0, 0, 0);
  }

  // ---- epilogue: branch-free totals + rare positive/diag path ----
  int lr[2][4], lc[4];
#pragma unroll
  for (int pi = 0; pi < 2; ++pi)
#pragma unroll
    for (int r = 0; r < 4; ++r) lr[pi][r] = labR[rbase + pi * 16 + quad * 4 + r];
#pragma unroll
  for (int pj = 0; pj < 4; ++pj) lc[pj] = labC[cbase + pj * 16 + l16];

  float trow[2][4] = {};
  float tcol[4] = {0.f, 0.f, 0.f, 0.f};
  float sacc = 0.f;
#pragma unroll
  for (int pi = 0; pi < 2; ++pi)
#pragma unroll
    for (int pj = 0; pj < 4; ++pj)
#pragma unroll
      for (int r = 0; r < 4; ++r) {
        const float s = acc[pi][pj][r];
        const float e = __expf(s);
        trow[pi][r] += e;
        tcol[pj] += e;
        if (lr[pi][r] == lc[pj]) {  // rare: 1/128
          const int row = rbase + pi * 16 + quad * 4 + r;
          const int col = cbase + pj * 16 + l16;
          if (offdiag) {
            atomicAdd(&psumS[row], e);
            atomicAdd(&psumS[128 + col], e);
            sacc += 2.f * s;
          } else if (row != col) {
            atomicAdd(&psumS[row], e);
            sacc += s;
          } else {
            diagS[row] = e;  // unique writer
          }
        }
      }

  // row sums: 4-shfl reduce over the 16 cols, stage in LDS
#pragma unroll
  for (int pi = 0; pi < 2; ++pi)
#pragma unroll
    for (int r = 0; r < 4; ++r) {
      float v = trow[pi][r];
      v += __shfl_xor(v, 1);
      v += __shfl_xor(v, 2);
      v += __shfl_xor(v, 4);
      v += __shfl_xor(v, 8);
      if (l16 == 0) atomicAdd(&tsumS[rbase + pi * 16 + quad * 4 + r], v);
    }
  // col sums (mirror band): reduce across quads, stage in LDS
#pragma unroll
  for (int pj = 0; pj < 4; ++pj) {
    float v = tcol[pj];
    v += __shfl_xor(v, 16);
    v += __shfl_xor(v, 32);
    if (quad == 0) atomicAdd(&tcolS[cbase + pj * 16 + l16], v);
  }
  // block scalar: sum_pos s
#pragma unroll
  for (int m = 1; m < 64; m <<= 1) sacc += __shfl_xor(sacc, m);
  if (lane == 0) sS[w] = sacc;
  __syncthreads();

  // flush: unsim += t - diag (so unsim = u + p), psum += p; one scalar atomic
  if (t < 128) {
    atomicAdd(&unsim[i0 + t], tsumS[t] - diagS[t]);
    atomicAdd(&psumG[i0 + t], psumS[t]);
  } else if (t < 256 && offdiag) {
    atomicAdd(&unsim[j0 + (t - 128)], tcolS[t - 128]);
    atomicAdd(&psumG[j0 + (t - 128)], psumS[t]);
  }
  if (t == 0) {
    float st = sS[0] + sS[1] + sS[2] + sS[3] + sS[4] + sS[5] + sS[6] + sS[7];
    atomicAdd(&accum[4], st);
  }
}

// ---------------------------------------------------------------------------
// Kernel 3: finalize (one 1024-thread block — 8 serial L2 iterations/thread):
//   loss_sum = sum_i [cnt_i*log(u_i) + p_i/u_i] - ssum,  u = unsim - p
//   n_pos    = sum_c m_c^2 - N;   out = loss_sum / n_pos
__global__ __launch_bounds__(1024) void finalize_kernel(
    const int* __restrict__ lab, const float* __restrict__ unsim,
    const float* __restrict__ psum, const float* __restrict__ accum,
    float* __restrict__ out, int N) {
  __shared__ int hist[256];
  __shared__ float redL[16], redN[16];
  int t = threadIdx.x;
  int lane = t & 63, w = t >> 6;
  if (t < 256) hist[t] = 0;
  __syncthreads();
  for (int i = t; i < N; i += 1024) atomicAdd(&hist[lab[i] & 255], 1);
  __syncthreads();
  float local = 0.f;
  for (int i = t; i < N; i += 1024) {
    float tot = unsim[i];
    float p = psum[i];
    float u = tot - p;
    float c = (float)(hist[lab[i] & 255] - 1);
    local += c * __logf(u) + p / u;
  }
  float nposl = 0.f;
  if (t < 256) {
    float m = (float)hist[t];
    nposl = m * m;
  }
#pragma unroll
  for (int msk = 1; msk < 64; msk <<= 1) {
    local += __shfl_xor(local, msk);
    nposl += __shfl_xor(nposl, msk);
  }
  if (lane == 0) {
    redL[w] = local;
    redN[w] = nposl;
  }
  __syncthreads();
  if (t == 0) {
    float ls = 0.f, np = 0.f;
#pragma unroll
    for (int i = 0; i < 16; ++i) {
      ls += redL[i];
      np += redN[i];
    }
    out[0] = (ls - accum[4]) / (np - (float)N);
  }
}

// ---------------------------------------------------------------------------
extern "C" void kernel_launch(void* const* d_in, const int* in_sizes, int n_in,
                              void* d_out, int out_size, void* d_ws,
                              size_t ws_size, hipStream_t stream) {
  const float* X = (const float*)d_in[0];
  const int* lab = (const int*)d_in[1];
  float* out = (float*)d_out;

  const int N = in_sizes[1];  // 8192; D fixed at 128

  // workspace layout
  unsigned char* Y8 = (unsigned char*)d_ws;       // N*128 fp8 (1 MB)
  float* unsim = (float*)(Y8 + (size_t)N * 128);  // N f32 (= u + p)
  float* psum = unsim + N;                        // N f32
  float* accum = psum + N;                        // [4] ssum

  const float inv_sqrtT = 2.2360679775f;  // 1/sqrt(0.2)
  norm_kernel<<<N / 8, 256, 0, stream>>>(X, Y8, unsim, psum, accum,
                                         inv_sqrtT);

  const int nt = N / 128;              // 64 tiles per dim
  const int nblk = nt * (nt + 1) / 2;  // 2080 upper-tri tile pairs
  pass1_kernel<<<nblk, 512, 0, stream>>>(Y8, lab, unsim, psum, accum, nt);
  finalize_kernel<<<1, 1024, 0, stream>>>(lab, unsim, psum, accum, out, N);
}